// Round 10
// baseline (319.615 us; speedup 1.0000x reference)
//
#include <hip/hip_runtime.h>
#include <hip/hip_bf16.h>
#include <math.h>

// VQ-VAE VectorQuantizer: B=32,T=2048,D=64,K=1024 -> N=65536 rows.
// Round 10: vq_exact rebuilt lanes=codes (coalesced e_T operand).
// Diagnosis: all lanes=rows scans (R1-R3 170us, R6/R8/R9 exact) share one
// bottleneck -- the wave-uniform e-row goes through the scalar/broadcast
// fetch path in SGPR-limited batches (~25-40cyc/element serialized).
// Fix: wave = one ambiguous row, lane = code; per d-step one coalesced
// e_T[d][ck*64+lane] load + one FMA; x broadcast in regs. Per-code rounding
// order UNCHANGED (sequential d=0..63 fmaf, fl(sx+se), fmaf(-2,acc,T), u64
// first-min keys). vq_fused / compact / finalize / EPSB frozen from R8/R9.

typedef __attribute__((ext_vector_type(8))) short bf16x8;
typedef __attribute__((ext_vector_type(4))) float f32x4;

namespace {
constexpr int NROWS  = 65536;
constexpr int DDIM   = 64;
constexpr int KCODES = 1024;
constexpr float EPSB = 8e-5f;   // certificate band; bound ~2.3e-5

// ws layout (bytes) — ~2.1 MB
constexpr size_t WS_LOSS = 0;                            // double
constexpr size_t WS_CNT  = 64;                           // int
constexpr size_t WS_SE   = 256;                          // float[1024]
constexpr size_t WS_EHB  = 8192;                         // bf16 frags 128 KB
constexpr size_t WS_ELB  = WS_EHB + (size_t)65536 * 2;   // 128 KB
constexpr size_t WS_BIDX = WS_ELB + (size_t)65536 * 2;   // int[N]
constexpr size_t WS_LIST = WS_BIDX + (size_t)NROWS * 4;  // int[N]
constexpr size_t WS_KEY  = WS_LIST + (size_t)NROWS * 4;  // u64[N]
constexpr size_t WS_ET   = WS_KEY + (size_t)NROWS * 8;   // float[64][1024] 256KB
}

__device__ inline short f2bf(float v) {
  __hip_bfloat16 h = __float2bfloat16(v);
  return *reinterpret_cast<short*>(&h);
}
__device__ inline float bf2f(short s) {
  __hip_bfloat16 h;
  *reinterpret_cast<short*>(&h) = s;
  return __bfloat162float(h);
}
__device__ inline f32x4 mfma16(bf16x8 a, bf16x8 b, f32x4 c) {
  return __builtin_amdgcn_mfma_f32_16x16x32_bf16(a, b, c, 0, 0, 0);
}
__device__ inline unsigned int fflip(unsigned int b) {
  return b ^ ((unsigned int)((int)b >> 31) | 0x80000000u);
}

// ---------------- prep: init, se (numpy pairwise), frag pack, e_T transpose
__global__ __launch_bounds__(256) void vq_prep(const float* __restrict__ emb,
                                               float* __restrict__ se,
                                               short* __restrict__ ehB,
                                               short* __restrict__ elB,
                                               float* __restrict__ e_t,
                                               unsigned long long* __restrict__ keyBest,
                                               double* __restrict__ loss_accum,
                                               int* __restrict__ cnt) {
  #pragma clang fp contract(off)
  const int gid = blockIdx.x * 256 + (int)threadIdx.x;   // grid = 65536
  if (gid == 0) { *loss_accum = 0.0; *cnt = 0; }
  keyBest[gid] = ~0ull;

  // e_T[d][j] = emb[j][d]; one element per thread (writes coalesced)
  {
    const int j = gid & 1023;
    const int d = gid >> 10;
    e_t[(size_t)d * KCODES + j] = emb[(size_t)j * DDIM + d];
  }

  if (gid < KCODES) {   // se[j]: proven pairwise pattern
    const float* e = emb + (size_t)gid * DDIM;
    float r[8];
    #pragma unroll
    for (int j = 0; j < 8; ++j) r[j] = e[j] * e[j];
    #pragma unroll
    for (int i = 8; i < DDIM; i += 8) {
      #pragma unroll
      for (int j = 0; j < 8; ++j) r[j] += e[i + j] * e[i + j];
    }
    se[gid] = ((r[0] + r[1]) + (r[2] + r[3])) + ((r[4] + r[5]) + (r[6] + r[7]));
  }

  // pack frag (t,dc): lane l holds e[t*16+(l&15)][dc*32+(l>>4)*8 + i]  (R5-R9)
  if (gid < 8192) {
    const int t  = gid >> 7;
    const int dc = (gid >> 6) & 1;
    const int l  = gid & 63;
    const int code = t * 16 + (l & 15);
    const int d0   = dc * 32 + (l >> 4) * 8;
    const float* ep = emb + (size_t)code * DDIM + d0;
    const size_t ob = ((size_t)(t * 2 + dc) * 64 + l) * 8;
    #pragma unroll
    for (int i = 0; i < 8; ++i) {
      const float v = ep[i];
      const short h = f2bf(v);
      ehB[ob + i] = h;
      elB[ob + i] = f2bf(v - bf2f(h));
    }
  }
}

// ---------------- fused sweep: wave = 32 rows x 1024 codes, 2-deep prefetch
__global__ __launch_bounds__(256, 2) void vq_fused(const float* __restrict__ x,
                                                   const short* __restrict__ ehB,
                                                   const short* __restrict__ elB,
                                                   const float* __restrict__ se,
                                                   int* __restrict__ bidx) {
  #pragma clang fp contract(off)
  __shared__ float sel[KCODES];
  const int tid = (int)threadIdx.x;
  const int l   = tid & 63;
  const int wid = tid >> 6;
  #pragma unroll
  for (int i = 0; i < 4; ++i) sel[i * 256 + tid] = se[i * 256 + tid];
  __syncthreads();

  // A-fragments for 2 row-tiles (32 rows/wave)
  const int wrb = blockIdx.x * 128 + wid * 32;
  bf16x8 xh[2][2], xl[2][2];
  #pragma unroll
  for (int rt = 0; rt < 2; ++rt) {
    const float* xp = x + (size_t)(wrb + rt * 16 + (l & 15)) * DDIM + (l >> 4) * 8;
    #pragma unroll
    for (int dc = 0; dc < 2; ++dc) {
      const float4 v0 = *reinterpret_cast<const float4*>(xp + dc * 32);
      const float4 v1 = *reinterpret_cast<const float4*>(xp + dc * 32 + 4);
      const float vv[8] = {v0.x, v0.y, v0.z, v0.w, v1.x, v1.y, v1.z, v1.w};
      #pragma unroll
      for (int i = 0; i < 8; ++i) {
        const short h = f2bf(vv[i]);
        xh[rt][dc][i] = h;
        xl[rt][dc][i] = f2bf(vv[i] - bf2f(h));
      }
    }
  }

  float m1v[2][4], m2v[2][4];
  int   m1t[2][4];
  #pragma unroll
  for (int rt = 0; rt < 2; ++rt)
    #pragma unroll
    for (int r = 0; r < 4; ++r) { m1v[rt][r] = INFINITY; m2v[rt][r] = INFINITY; m1t[rt][r] = 0; }

  const size_t lb = (size_t)l * 8;
#define FRAGLD(buf, tt, half) \
  (*reinterpret_cast<const bf16x8*>((buf) + (size_t)(tt) * 1024 + (half) * 512 + lb))

  // 2-deep pipeline: tiles t (cur) / t+1 (nxt) in flight while computing.
  bf16x8 c0 = FRAGLD(ehB, 0, 0), c1 = FRAGLD(ehB, 0, 1),
         c2 = FRAGLD(elB, 0, 0), c3 = FRAGLD(elB, 0, 1);
  bf16x8 n0 = FRAGLD(ehB, 1, 0), n1 = FRAGLD(ehB, 1, 1),
         n2 = FRAGLD(elB, 1, 0), n3 = FRAGLD(elB, 1, 1);

  const f32x4 kz = {0.f, 0.f, 0.f, 0.f};
  #pragma unroll 4
  for (int t = 0; t < 64; ++t) {
    const int tf = (t + 2 < 64) ? t + 2 : 63;   // clamp (dup loads harmless)
    bf16x8 f0 = FRAGLD(ehB, tf, 0), f1 = FRAGLD(ehB, tf, 1),
           f2 = FRAGLD(elB, tf, 0), f3 = FRAGLD(elB, tf, 1);

    f32x4 a0, a1;   // interleave the two row-tiles: dep distance 2 on MFMA pipe
    a0 = mfma16(xh[0][0], c0, kz);  a1 = mfma16(xh[1][0], c0, kz);
    a0 = mfma16(xh[0][1], c1, a0);  a1 = mfma16(xh[1][1], c1, a1);
    a0 = mfma16(xh[0][0], c2, a0);  a1 = mfma16(xh[1][0], c2, a1);
    a0 = mfma16(xh[0][1], c3, a0);  a1 = mfma16(xh[1][1], c3, a1);
    a0 = mfma16(xl[0][0], c0, a0);  a1 = mfma16(xl[1][0], c0, a1);
    a0 = mfma16(xl[0][1], c1, a0);  a1 = mfma16(xl[1][1], c1, a1);

    const float sev = sel[t * 16 + (l & 15)];
    #pragma unroll
    for (int r = 0; r < 4; ++r) {
      {
        const float d = __builtin_fmaf(-2.0f, a0[r], sev);  // d' = se - 2*dot
        const bool c = d < m1v[0][r];
        m2v[0][r] = fminf(m2v[0][r], fmaxf(m1v[0][r], d));
        m1t[0][r] = c ? t : m1t[0][r];
        m1v[0][r] = fminf(m1v[0][r], d);
      }
      {
        const float d = __builtin_fmaf(-2.0f, a1[r], sev);
        const bool c = d < m1v[1][r];
        m2v[1][r] = fminf(m2v[1][r], fmaxf(m1v[1][r], d));
        m1t[1][r] = c ? t : m1t[1][r];
        m1v[1][r] = fminf(m1v[1][r], d);
      }
    }
    c0 = n0; c1 = n1; c2 = n2; c3 = n3;
    n0 = f0; n1 = f1; n2 = f2; n3 = f3;
  }
#undef FRAGLD

  // 16-lane merge (R6-R9-proven); certificate or sentinel
  const int colbase = l & 15;
  #pragma unroll
  for (int rt = 0; rt < 2; ++rt) {
    #pragma unroll
    for (int r = 0; r < 4; ++r) {
      float m1 = m1v[rt][r], m2 = m2v[rt][r];
      unsigned long long key =
          ((unsigned long long)fflip(__float_as_uint(m1)) << 32)
          | (unsigned)(m1t[rt][r] * 16 + colbase);
      #pragma unroll
      for (int off = 1; off < 16; off <<= 1) {
        const unsigned long long ok = __shfl_xor(key, off, 16);
        const float om1 = __shfl_xor(m1, off, 16);
        const float om2 = __shfl_xor(m2, off, 16);
        m2 = fminf(fminf(m2, om2), fmaxf(m1, om1));
        m1 = fminf(m1, om1);
        key = (ok < key) ? ok : key;
      }
      if (colbase == 0) {
        const int row = wrb + rt * 16 + (l >> 4) * 4 + r;
        bidx[row] = (m2 > m1 + EPSB) ? (int)(key & 0xffffffffull) : -1;
      }
    }
  }
}

// ---------------- compact: gather ambiguous rows, <=1 atomic per wave
__global__ __launch_bounds__(256) void vq_compact(const int* __restrict__ bidx,
                                                  int* __restrict__ list,
                                                  int* __restrict__ cnt) {
  const int gid = blockIdx.x * 256 + (int)threadIdx.x;
  const int l = (int)threadIdx.x & 63;
  const bool amb = bidx[gid] < 0;
  const unsigned long long mask = __ballot(amb);
  int base = 0;
  if (l == 0 && mask) base = atomicAdd(cnt, (int)__popcll(mask));
  base = __shfl(base, 0, 64);
  if (amb) {
    const int off = (int)__popcll(mask & ((1ull << l) - 1ull));
    list[base + off] = gid;
  }
}

// ---------------- exact scan: wave = one ambiguous row, lanes = codes.
// Coalesced e_T column loads; x broadcast in regs. Bit-exact R1 chain.
__global__ __launch_bounds__(256) void vq_exact(const float* __restrict__ x,
                                                const float* __restrict__ e_t,
                                                const float* __restrict__ se,
                                                const int* __restrict__ list,
                                                const int* __restrict__ cnt,
                                                unsigned long long* __restrict__ keyBest) {
  #pragma clang fp contract(off)
  const int n = *cnt;
  const int nW = (int)gridDim.x * 4;                     // 4096 waves
  const int w  = blockIdx.x * 4 + ((int)threadIdx.x >> 6);
  const int l  = (int)threadIdx.x & 63;

  for (int task = w; task < n; task += nW) {
    const int row = list[task];
    const float4* xr4 = reinterpret_cast<const float4*>(x + (size_t)row * DDIM);

    // x row -> regs (uniform loads, broadcast to all lanes)
    float xv[DDIM];
    #pragma unroll
    for (int q = 0; q < 16; ++q) {
      const float4 v = xr4[q];
      xv[q * 4 + 0] = v.x; xv[q * 4 + 1] = v.y;
      xv[q * 4 + 2] = v.z; xv[q * 4 + 3] = v.w;
    }

    // sx: numpy pairwise 8-accumulator (R1-proven order)
    float rr[8];
    #pragma unroll
    for (int j = 0; j < 8; ++j) rr[j] = xv[j] * xv[j];
    #pragma unroll
    for (int i = 8; i < DDIM; i += 8) {
      #pragma unroll
      for (int j = 0; j < 8; ++j) rr[j] += xv[i + j] * xv[i + j];
    }
    const float sx = ((rr[0] + rr[1]) + (rr[2] + rr[3])) + ((rr[4] + rr[5]) + (rr[6] + rr[7]));

    unsigned long long best = ~0ull;
    #pragma unroll 1
    for (int ck = 0; ck < 16; ck += 2) {   // 2 chunks in flight (2 chains)
      const int j0 = ck * 64 + l;
      const int j1 = j0 + 64;
      const float* c0 = e_t + j0;          // column loads: coalesced per d
      const float* c1 = e_t + j1;
      float a0 = 0.f, a1 = 0.f;
      #pragma unroll
      for (int d = 0; d < DDIM; ++d) {     // sequential d=0..63 per code (R1)
        a0 = __builtin_fmaf(xv[d], c0[(size_t)d * KCODES], a0);
        a1 = __builtin_fmaf(xv[d], c1[(size_t)d * KCODES], a1);
      }
      const float T0 = sx + se[j0];                       // fl(sx + se_j)
      const float T1 = sx + se[j1];
      const float di0 = __builtin_fmaf(-2.0f, a0, T0);    // fl(T - 2*acc)
      const float di1 = __builtin_fmaf(-2.0f, a1, T1);
      unsigned long long k;
      k = ((unsigned long long)fflip(__float_as_uint(di0)) << 32) | (unsigned)j0;
      best = (k < best) ? k : best;
      k = ((unsigned long long)fflip(__float_as_uint(di1)) << 32) | (unsigned)j1;
      best = (k < best) ? k : best;
    }
    // 64-lane min: (dist asc, j asc) == first-min
    #pragma unroll
    for (int off = 32; off > 0; off >>= 1) {
      const unsigned long long o = __shfl_xor(best, off, 64);
      best = (o < best) ? o : best;
    }
    if (l == 0) keyBest[row] = best;   // single writer per row
  }
}

// ---------------- finalize: 16 lanes x float4 per row (coalesced e-gather)
__global__ __launch_bounds__(256) void vq_finalize(const float* __restrict__ x,
                                                   const float* __restrict__ emb,
                                                   const int* __restrict__ bidx,
                                                   const unsigned long long* __restrict__ keyBest,
                                                   float* __restrict__ out,
                                                   double* __restrict__ loss_accum) {
  #pragma clang fp contract(off)
  __shared__ float wsum[4];
  const int tid = (int)threadIdx.x;
  const int l   = tid & 63;
  const int wid = tid >> 6;
  const int sub = l >> 4;    // row within the wave's quad
  const int q16 = l & 15;    // float4 slot within the row
  float lacc = 0.f;

  #pragma unroll
  for (int it = 0; it < 4; ++it) {   // block covers 64 rows
    const int row = blockIdx.x * 64 + it * 16 + wid * 4 + sub;
    int bi = bidx[row];
    if (bi < 0) bi = (int)(keyBest[row] & 0xffffffffull);
    const float4 xv = reinterpret_cast<const float4*>(x)[(size_t)row * 16 + q16];
    const float4 ev = reinterpret_cast<const float4*>(emb)[(size_t)bi * 16 + q16];
    const float da = ev.x - xv.x;
    const float db = ev.y - xv.y;
    const float dc = ev.z - xv.z;
    const float dd = ev.w - xv.w;
    float4 o;
    o.x = xv.x + da; o.y = xv.y + db; o.z = xv.z + dc; o.w = xv.w + dd;
    reinterpret_cast<float4*>(out)[(size_t)row * 16 + q16] = o;
    lacc += da * da + db * db + dc * dc + dd * dd;   // order-insensitive
    if (q16 == 0) out[(size_t)NROWS * DDIM + row] = (float)bi;
  }
  #pragma unroll
  for (int off = 32; off > 0; off >>= 1) lacc += __shfl_down(lacc, off, 64);
  if (l == 0) wsum[wid] = lacc;
  __syncthreads();
  if (tid == 0)
    atomicAdd(loss_accum, (double)(wsum[0] + wsum[1] + wsum[2] + wsum[3]));
}

// ---------------- scalars
__global__ void vq_scalars(const double* __restrict__ loss_accum,
                           float* __restrict__ out) {
  if (threadIdx.x == 0 && blockIdx.x == 0) {
    const double mm = *loss_accum / (double)((size_t)NROWS * DDIM);
    const float el = (float)mm;
    float* tail = out + (size_t)NROWS * DDIM + NROWS;
    tail[0] = 0.25f * el;
    tail[1] = el;
    tail[2] = 0.0f;
  }
}

// ============================================================================
extern "C" void kernel_launch(void* const* d_in, const int* in_sizes, int n_in,
                              void* d_out, int out_size, void* d_ws, size_t ws_size,
                              hipStream_t stream) {
  const float* x   = (const float*)d_in[0];  // [N, 64]
  const float* emb = (const float*)d_in[1];  // [K, 64]
  float* out = (float*)d_out;
  char* ws = (char*)d_ws;

  double* loss_accum = (double*)(ws + WS_LOSS);
  int*    cnt        = (int*)(ws + WS_CNT);
  float*  se         = (float*)(ws + WS_SE);
  short*  ehB        = (short*)(ws + WS_EHB);
  short*  elB        = (short*)(ws + WS_ELB);
  int*    bidx       = (int*)(ws + WS_BIDX);
  int*    list       = (int*)(ws + WS_LIST);
  unsigned long long* keyBest = (unsigned long long*)(ws + WS_KEY);
  float*  e_t        = (float*)(ws + WS_ET);

  vq_prep<<<NROWS / 256, 256, 0, stream>>>(emb, se, ehB, elB, e_t, keyBest,
                                           loss_accum, cnt);
  vq_fused<<<NROWS / 128, 256, 0, stream>>>(x, ehB, elB, se, bidx);
  vq_compact<<<NROWS / 256, 256, 0, stream>>>(bidx, list, cnt);
  vq_exact<<<1024, 256, 0, stream>>>(x, e_t, se, list, cnt, keyBest);
  vq_finalize<<<NROWS / 64, 256, 0, stream>>>(x, emb, bidx, keyBest, out,
                                              loss_accum);
  vq_scalars<<<1, 64, 0, stream>>>(loss_accum, out);
}

// Round 11
// 124.915 us; speedup vs baseline: 2.5587x; 2.5587x over previous
//
#include <hip/hip_runtime.h>
#include <hip/hip_bf16.h>
#include <math.h>

// VQ-VAE VectorQuantizer: B=32,T=2048,D=64,K=1024 -> N=65536 rows.
// Round 11: vq_exact rebuilt as lanes=rows + LDS-staged e (hardware broadcast).
// History: lanes=rows + scalar e-path serialized (R1-3/8/9: 68-170us);
// lanes=codes re-read 256KB/row (R10: 239us). LDS staging amortizes e across
// a block's 256 rows: block = 256 rows x 64-code partition (16KB LDS),
// grid = 32 rowblk x 16 parts. Per-code rounding order UNCHANGED (sequential
// d=0..63 fmaf via float4 lanes, fl(sx+se), fmaf(-2,acc,T), u64 first-min,
// atomicMin merge). vq_fused / prep / compact / finalize frozen (R8/R9).

typedef __attribute__((ext_vector_type(8))) short bf16x8;
typedef __attribute__((ext_vector_type(4))) float f32x4;

namespace {
constexpr int NROWS  = 65536;
constexpr int DDIM   = 64;
constexpr int KCODES = 1024;
constexpr float EPSB = 8e-5f;   // certificate band; bound ~2.3e-5

// ws layout (bytes) — ~1.8 MB
constexpr size_t WS_LOSS = 0;                            // double
constexpr size_t WS_CNT  = 64;                           // int
constexpr size_t WS_SE   = 256;                          // float[1024]
constexpr size_t WS_EHB  = 8192;                         // bf16 frags 128 KB
constexpr size_t WS_ELB  = WS_EHB + (size_t)65536 * 2;   // 128 KB
constexpr size_t WS_BIDX = WS_ELB + (size_t)65536 * 2;   // int[N]
constexpr size_t WS_LIST = WS_BIDX + (size_t)NROWS * 4;  // int[N]
constexpr size_t WS_KEY  = WS_LIST + (size_t)NROWS * 4;  // u64[N]
}

__device__ inline short f2bf(float v) {
  __hip_bfloat16 h = __float2bfloat16(v);
  return *reinterpret_cast<short*>(&h);
}
__device__ inline float bf2f(short s) {
  __hip_bfloat16 h;
  *reinterpret_cast<short*>(&h) = s;
  return __bfloat162float(h);
}
__device__ inline f32x4 mfma16(bf16x8 a, bf16x8 b, f32x4 c) {
  return __builtin_amdgcn_mfma_f32_16x16x32_bf16(a, b, c, 0, 0, 0);
}
__device__ inline unsigned int fflip(unsigned int b) {
  return b ^ ((unsigned int)((int)b >> 31) | 0x80000000u);
}

// ---------------- prep: init keyBest/loss/cnt, se (numpy pairwise), frag pack
__global__ __launch_bounds__(256) void vq_prep(const float* __restrict__ emb,
                                               float* __restrict__ se,
                                               short* __restrict__ ehB,
                                               short* __restrict__ elB,
                                               unsigned long long* __restrict__ keyBest,
                                               double* __restrict__ loss_accum,
                                               int* __restrict__ cnt) {
  #pragma clang fp contract(off)
  const int gid = blockIdx.x * 256 + (int)threadIdx.x;   // grid = 65536
  if (gid == 0) { *loss_accum = 0.0; *cnt = 0; }
  keyBest[gid] = ~0ull;

  if (gid < KCODES) {   // se[j]: proven pairwise pattern
    const float* e = emb + (size_t)gid * DDIM;
    float r[8];
    #pragma unroll
    for (int j = 0; j < 8; ++j) r[j] = e[j] * e[j];
    #pragma unroll
    for (int i = 8; i < DDIM; i += 8) {
      #pragma unroll
      for (int j = 0; j < 8; ++j) r[j] += e[i + j] * e[i + j];
    }
    se[gid] = ((r[0] + r[1]) + (r[2] + r[3])) + ((r[4] + r[5]) + (r[6] + r[7]));
  }

  // pack frag (t,dc): lane l holds e[t*16+(l&15)][dc*32+(l>>4)*8 + i]  (R5-R10)
  if (gid < 8192) {
    const int t  = gid >> 7;
    const int dc = (gid >> 6) & 1;
    const int l  = gid & 63;
    const int code = t * 16 + (l & 15);
    const int d0   = dc * 32 + (l >> 4) * 8;
    const float* ep = emb + (size_t)code * DDIM + d0;
    const size_t ob = ((size_t)(t * 2 + dc) * 64 + l) * 8;
    #pragma unroll
    for (int i = 0; i < 8; ++i) {
      const float v = ep[i];
      const short h = f2bf(v);
      ehB[ob + i] = h;
      elB[ob + i] = f2bf(v - bf2f(h));
    }
  }
}

// ---------------- fused sweep: wave = 32 rows x 1024 codes, 2-deep prefetch
__global__ __launch_bounds__(256, 2) void vq_fused(const float* __restrict__ x,
                                                   const short* __restrict__ ehB,
                                                   const short* __restrict__ elB,
                                                   const float* __restrict__ se,
                                                   int* __restrict__ bidx) {
  #pragma clang fp contract(off)
  __shared__ float sel[KCODES];
  const int tid = (int)threadIdx.x;
  const int l   = tid & 63;
  const int wid = tid >> 6;
  #pragma unroll
  for (int i = 0; i < 4; ++i) sel[i * 256 + tid] = se[i * 256 + tid];
  __syncthreads();

  // A-fragments for 2 row-tiles (32 rows/wave)
  const int wrb = blockIdx.x * 128 + wid * 32;
  bf16x8 xh[2][2], xl[2][2];
  #pragma unroll
  for (int rt = 0; rt < 2; ++rt) {
    const float* xp = x + (size_t)(wrb + rt * 16 + (l & 15)) * DDIM + (l >> 4) * 8;
    #pragma unroll
    for (int dc = 0; dc < 2; ++dc) {
      const float4 v0 = *reinterpret_cast<const float4*>(xp + dc * 32);
      const float4 v1 = *reinterpret_cast<const float4*>(xp + dc * 32 + 4);
      const float vv[8] = {v0.x, v0.y, v0.z, v0.w, v1.x, v1.y, v1.z, v1.w};
      #pragma unroll
      for (int i = 0; i < 8; ++i) {
        const short h = f2bf(vv[i]);
        xh[rt][dc][i] = h;
        xl[rt][dc][i] = f2bf(vv[i] - bf2f(h));
      }
    }
  }

  float m1v[2][4], m2v[2][4];
  int   m1t[2][4];
  #pragma unroll
  for (int rt = 0; rt < 2; ++rt)
    #pragma unroll
    for (int r = 0; r < 4; ++r) { m1v[rt][r] = INFINITY; m2v[rt][r] = INFINITY; m1t[rt][r] = 0; }

  const size_t lb = (size_t)l * 8;
#define FRAGLD(buf, tt, half) \
  (*reinterpret_cast<const bf16x8*>((buf) + (size_t)(tt) * 1024 + (half) * 512 + lb))

  // 2-deep pipeline: tiles t (cur) / t+1 (nxt) in flight while computing.
  bf16x8 c0 = FRAGLD(ehB, 0, 0), c1 = FRAGLD(ehB, 0, 1),
         c2 = FRAGLD(elB, 0, 0), c3 = FRAGLD(elB, 0, 1);
  bf16x8 n0 = FRAGLD(ehB, 1, 0), n1 = FRAGLD(ehB, 1, 1),
         n2 = FRAGLD(elB, 1, 0), n3 = FRAGLD(elB, 1, 1);

  const f32x4 kz = {0.f, 0.f, 0.f, 0.f};
  #pragma unroll 4
  for (int t = 0; t < 64; ++t) {
    const int tf = (t + 2 < 64) ? t + 2 : 63;   // clamp (dup loads harmless)
    bf16x8 f0 = FRAGLD(ehB, tf, 0), f1 = FRAGLD(ehB, tf, 1),
           f2 = FRAGLD(elB, tf, 0), f3 = FRAGLD(elB, tf, 1);

    f32x4 a0, a1;   // interleave the two row-tiles: dep distance 2 on MFMA pipe
    a0 = mfma16(xh[0][0], c0, kz);  a1 = mfma16(xh[1][0], c0, kz);
    a0 = mfma16(xh[0][1], c1, a0);  a1 = mfma16(xh[1][1], c1, a1);
    a0 = mfma16(xh[0][0], c2, a0);  a1 = mfma16(xh[1][0], c2, a1);
    a0 = mfma16(xh[0][1], c3, a0);  a1 = mfma16(xh[1][1], c3, a1);
    a0 = mfma16(xl[0][0], c0, a0);  a1 = mfma16(xl[1][0], c0, a1);
    a0 = mfma16(xl[0][1], c1, a0);  a1 = mfma16(xl[1][1], c1, a1);

    const float sev = sel[t * 16 + (l & 15)];
    #pragma unroll
    for (int r = 0; r < 4; ++r) {
      {
        const float d = __builtin_fmaf(-2.0f, a0[r], sev);  // d' = se - 2*dot
        const bool c = d < m1v[0][r];
        m2v[0][r] = fminf(m2v[0][r], fmaxf(m1v[0][r], d));
        m1t[0][r] = c ? t : m1t[0][r];
        m1v[0][r] = fminf(m1v[0][r], d);
      }
      {
        const float d = __builtin_fmaf(-2.0f, a1[r], sev);
        const bool c = d < m1v[1][r];
        m2v[1][r] = fminf(m2v[1][r], fmaxf(m1v[1][r], d));
        m1t[1][r] = c ? t : m1t[1][r];
        m1v[1][r] = fminf(m1v[1][r], d);
      }
    }
    c0 = n0; c1 = n1; c2 = n2; c3 = n3;
    n0 = f0; n1 = f1; n2 = f2; n3 = f3;
  }
#undef FRAGLD

  // 16-lane merge (R6-R10-proven); certificate or sentinel
  const int colbase = l & 15;
  #pragma unroll
  for (int rt = 0; rt < 2; ++rt) {
    #pragma unroll
    for (int r = 0; r < 4; ++r) {
      float m1 = m1v[rt][r], m2 = m2v[rt][r];
      unsigned long long key =
          ((unsigned long long)fflip(__float_as_uint(m1)) << 32)
          | (unsigned)(m1t[rt][r] * 16 + colbase);
      #pragma unroll
      for (int off = 1; off < 16; off <<= 1) {
        const unsigned long long ok = __shfl_xor(key, off, 16);
        const float om1 = __shfl_xor(m1, off, 16);
        const float om2 = __shfl_xor(m2, off, 16);
        m2 = fminf(fminf(m2, om2), fmaxf(m1, om1));
        m1 = fminf(m1, om1);
        key = (ok < key) ? ok : key;
      }
      if (colbase == 0) {
        const int row = wrb + rt * 16 + (l >> 4) * 4 + r;
        bidx[row] = (m2 > m1 + EPSB) ? (int)(key & 0xffffffffull) : -1;
      }
    }
  }
}

// ---------------- compact: gather ambiguous rows, <=1 atomic per wave
__global__ __launch_bounds__(256) void vq_compact(const int* __restrict__ bidx,
                                                  int* __restrict__ list,
                                                  int* __restrict__ cnt) {
  const int gid = blockIdx.x * 256 + (int)threadIdx.x;
  const int l = (int)threadIdx.x & 63;
  const bool amb = bidx[gid] < 0;
  const unsigned long long mask = __ballot(amb);
  int base = 0;
  if (l == 0 && mask) base = atomicAdd(cnt, (int)__popcll(mask));
  base = __shfl(base, 0, 64);
  if (amb) {
    const int off = (int)__popcll(mask & ((1ull << l) - 1ull));
    list[base + off] = gid;
  }
}

// ---------------- exact scan: lanes = rows, e staged in LDS (broadcast reads).
// Block = 256 rows x one 64-code partition; grid = 32 rowblk x 16 parts.
__global__ __launch_bounds__(256) void vq_exact(const float* __restrict__ x,
                                                const float* __restrict__ emb,
                                                const float* __restrict__ se,
                                                const int* __restrict__ list,
                                                const int* __restrict__ cnt,
                                                unsigned long long* __restrict__ keyBest) {
  #pragma clang fp contract(off)
  __shared__ __align__(16) float eL[64 * DDIM];   // 16 KB: this part's 64 codes
  const int part = (int)blockIdx.x & 15;
  const int j0 = part * 64;

  {  // stage: 64 contiguous e-rows, coalesced float4 copy
    const float4* src = reinterpret_cast<const float4*>(emb + (size_t)j0 * DDIM);
    float4* dst = reinterpret_cast<float4*>(eL);
    #pragma unroll
    for (int i = 0; i < 4; ++i)
      dst[i * 256 + (int)threadIdx.x] = src[i * 256 + (int)threadIdx.x];
  }
  __syncthreads();

  const int n = *cnt;
  const int l  = (int)threadIdx.x & 63;
  const int wv = (int)threadIdx.x >> 6;

  for (int rb = (int)blockIdx.x >> 4; rb * 256 < n; rb += 32) {
    const int idx = rb * 256 + wv * 64 + l;
    const bool act = idx < n;
    const int row = act ? list[idx] : list[0];
    const float4* xr4 = reinterpret_cast<const float4*>(x + (size_t)row * DDIM);

    float xv[DDIM];   // x row -> regs once
    #pragma unroll
    for (int q = 0; q < 16; ++q) {
      const float4 v = xr4[q];
      xv[q * 4 + 0] = v.x; xv[q * 4 + 1] = v.y;
      xv[q * 4 + 2] = v.z; xv[q * 4 + 3] = v.w;
    }

    // sx: numpy pairwise 8-accumulator (R1-proven order)
    float rr[8];
    #pragma unroll
    for (int j = 0; j < 8; ++j) rr[j] = xv[j] * xv[j];
    #pragma unroll
    for (int i = 8; i < DDIM; i += 8) {
      #pragma unroll
      for (int j = 0; j < 8; ++j) rr[j] += xv[i + j] * xv[i + j];
    }
    const float sx = ((rr[0] + rr[1]) + (rr[2] + rr[3])) + ((rr[4] + rr[5]) + (rr[6] + rr[7]));

    unsigned long long best = ~0ull;
    #pragma unroll 1
    for (int g = 0; g < 16; ++g) {   // 16 groups of 4 codes; 4 chains
      const int jb = g * 4;
      const float4* e0 = reinterpret_cast<const float4*>(eL + (jb + 0) * DDIM);
      const float4* e1 = reinterpret_cast<const float4*>(eL + (jb + 1) * DDIM);
      const float4* e2 = reinterpret_cast<const float4*>(eL + (jb + 2) * DDIM);
      const float4* e3 = reinterpret_cast<const float4*>(eL + (jb + 3) * DDIM);
      float a0 = 0.f, a1 = 0.f, a2 = 0.f, a3 = 0.f;
      #pragma unroll
      for (int q = 0; q < 16; ++q) {   // per code: sequential d=0..63 (R1 chain)
        const float4 v0 = e0[q], v1 = e1[q], v2 = e2[q], v3 = e3[q];
        const float xa = xv[q * 4 + 0], xb = xv[q * 4 + 1];
        const float xc = xv[q * 4 + 2], xd = xv[q * 4 + 3];
        a0 = __builtin_fmaf(xa, v0.x, a0); a0 = __builtin_fmaf(xb, v0.y, a0);
        a0 = __builtin_fmaf(xc, v0.z, a0); a0 = __builtin_fmaf(xd, v0.w, a0);
        a1 = __builtin_fmaf(xa, v1.x, a1); a1 = __builtin_fmaf(xb, v1.y, a1);
        a1 = __builtin_fmaf(xc, v1.z, a1); a1 = __builtin_fmaf(xd, v1.w, a1);
        a2 = __builtin_fmaf(xa, v2.x, a2); a2 = __builtin_fmaf(xb, v2.y, a2);
        a2 = __builtin_fmaf(xc, v2.z, a2); a2 = __builtin_fmaf(xd, v2.w, a2);
        a3 = __builtin_fmaf(xa, v3.x, a3); a3 = __builtin_fmaf(xb, v3.y, a3);
        a3 = __builtin_fmaf(xc, v3.z, a3); a3 = __builtin_fmaf(xd, v3.w, a3);
      }
      const int j = j0 + jb;
      const float T0 = sx + se[j + 0];                    // fl(sx + se_j)
      const float T1 = sx + se[j + 1];
      const float T2 = sx + se[j + 2];
      const float T3 = sx + se[j + 3];
      const float di0 = __builtin_fmaf(-2.0f, a0, T0);    // fl(T - 2*acc)
      const float di1 = __builtin_fmaf(-2.0f, a1, T1);
      const float di2 = __builtin_fmaf(-2.0f, a2, T2);
      const float di3 = __builtin_fmaf(-2.0f, a3, T3);
      unsigned long long k;
      k = ((unsigned long long)fflip(__float_as_uint(di0)) << 32) | (unsigned)(j + 0);
      best = (k < best) ? k : best;
      k = ((unsigned long long)fflip(__float_as_uint(di1)) << 32) | (unsigned)(j + 1);
      best = (k < best) ? k : best;
      k = ((unsigned long long)fflip(__float_as_uint(di2)) << 32) | (unsigned)(j + 2);
      best = (k < best) ? k : best;
      k = ((unsigned long long)fflip(__float_as_uint(di3)) << 32) | (unsigned)(j + 3);
      best = (k < best) ? k : best;
    }
    if (act) atomicMin(&keyBest[row], best);   // (dist asc, j asc) == first-min
  }
}

// ---------------- finalize: 16 lanes x float4 per row (coalesced e-gather)
__global__ __launch_bounds__(256) void vq_finalize(const float* __restrict__ x,
                                                   const float* __restrict__ emb,
                                                   const int* __restrict__ bidx,
                                                   const unsigned long long* __restrict__ keyBest,
                                                   float* __restrict__ out,
                                                   double* __restrict__ loss_accum) {
  #pragma clang fp contract(off)
  __shared__ float wsum[4];
  const int tid = (int)threadIdx.x;
  const int l   = tid & 63;
  const int wid = tid >> 6;
  const int sub = l >> 4;    // row within the wave's quad
  const int q16 = l & 15;    // float4 slot within the row
  float lacc = 0.f;

  #pragma unroll
  for (int it = 0; it < 4; ++it) {   // block covers 64 rows
    const int row = blockIdx.x * 64 + it * 16 + wid * 4 + sub;
    int bi = bidx[row];
    if (bi < 0) bi = (int)(keyBest[row] & 0xffffffffull);
    const float4 xv = reinterpret_cast<const float4*>(x)[(size_t)row * 16 + q16];
    const float4 ev = reinterpret_cast<const float4*>(emb)[(size_t)bi * 16 + q16];
    const float da = ev.x - xv.x;
    const float db = ev.y - xv.y;
    const float dc = ev.z - xv.z;
    const float dd = ev.w - xv.w;
    float4 o;
    o.x = xv.x + da; o.y = xv.y + db; o.z = xv.z + dc; o.w = xv.w + dd;
    reinterpret_cast<float4*>(out)[(size_t)row * 16 + q16] = o;
    lacc += da * da + db * db + dc * dc + dd * dd;   // order-insensitive
    if (q16 == 0) out[(size_t)NROWS * DDIM + row] = (float)bi;
  }
  #pragma unroll
  for (int off = 32; off > 0; off >>= 1) lacc += __shfl_down(lacc, off, 64);
  if (l == 0) wsum[wid] = lacc;
  __syncthreads();
  if (tid == 0)
    atomicAdd(loss_accum, (double)(wsum[0] + wsum[1] + wsum[2] + wsum[3]));
}

// ---------------- scalars
__global__ void vq_scalars(const double* __restrict__ loss_accum,
                           float* __restrict__ out) {
  if (threadIdx.x == 0 && blockIdx.x == 0) {
    const double mm = *loss_accum / (double)((size_t)NROWS * DDIM);
    const float el = (float)mm;
    float* tail = out + (size_t)NROWS * DDIM + NROWS;
    tail[0] = 0.25f * el;
    tail[1] = el;
    tail[2] = 0.0f;
  }
}

// ============================================================================
extern "C" void kernel_launch(void* const* d_in, const int* in_sizes, int n_in,
                              void* d_out, int out_size, void* d_ws, size_t ws_size,
                              hipStream_t stream) {
  const float* x   = (const float*)d_in[0];  // [N, 64]
  const float* emb = (const float*)d_in[1];  // [K, 64]
  float* out = (float*)d_out;
  char* ws = (char*)d_ws;

  double* loss_accum = (double*)(ws + WS_LOSS);
  int*    cnt        = (int*)(ws + WS_CNT);
  float*  se         = (float*)(ws + WS_SE);
  short*  ehB        = (short*)(ws + WS_EHB);
  short*  elB        = (short*)(ws + WS_ELB);
  int*    bidx       = (int*)(ws + WS_BIDX);
  int*    list       = (int*)(ws + WS_LIST);
  unsigned long long* keyBest = (unsigned long long*)(ws + WS_KEY);

  vq_prep<<<NROWS / 256, 256, 0, stream>>>(emb, se, ehB, elB, keyBest,
                                           loss_accum, cnt);
  vq_fused<<<NROWS / 128, 256, 0, stream>>>(x, ehB, elB, se, bidx);
  vq_compact<<<NROWS / 256, 256, 0, stream>>>(bidx, list, cnt);
  vq_exact<<<512, 256, 0, stream>>>(x, emb, se, list, cnt, keyBest);
  vq_finalize<<<NROWS / 64, 256, 0, stream>>>(x, emb, bidx, keyBest, out,
                                              loss_accum);
  vq_scalars<<<1, 64, 0, stream>>>(loss_accum, out);
}

// Round 12
// 112.084 us; speedup vs baseline: 2.8516x; 1.1145x over previous
//
#include <hip/hip_runtime.h>
#include <hip/hip_bf16.h>
#include <math.h>

// VQ-VAE VectorQuantizer: B=32,T=2048,D=64,K=1024 -> N=65536 rows.
// Round 12: two structural changes to R11 (124.9us, absmax 0.0):
//  1) EPSB 8e-5 -> 4e-5 (error budget |d' - (dist-sx)| <= ~1.05e-5; 2x margin
//     on 2x the conservative bound). Ambiguous n ~7.7k -> ~4k, halving exact.
//  2) vq_fused K-split x2: block = 128 rows x 512 codes, grid 1024 (occupancy
//     cap 25%->50%, the measured limiter). Partials (m1,m2,key) per half;
//     combine rule m2g=min(min(m2a,m2b),max(m1a,m1b)), kg=min(kA,kB) folded
//     into the compaction kernel. Certificate semantics unchanged.
// vq_exact / finalize / prep / scalars byte-frozen from R11 (absmax 0.0).

typedef __attribute__((ext_vector_type(8))) short bf16x8;
typedef __attribute__((ext_vector_type(4))) float f32x4;

namespace {
constexpr int NROWS  = 65536;
constexpr int DDIM   = 64;
constexpr int KCODES = 1024;
constexpr float EPSB = 4e-5f;   // certificate band; bound ~1.05e-5

// ws layout (bytes) — ~3.3 MB
constexpr size_t WS_LOSS = 0;                            // double
constexpr size_t WS_CNT  = 64;                           // int
constexpr size_t WS_SE   = 256;                          // float[1024]
constexpr size_t WS_EHB  = 8192;                         // bf16 frags 128 KB
constexpr size_t WS_ELB  = WS_EHB + (size_t)65536 * 2;   // 128 KB
constexpr size_t WS_BIDX = WS_ELB + (size_t)65536 * 2;   // int[N]
constexpr size_t WS_LIST = WS_BIDX + (size_t)NROWS * 4;  // int[N]
constexpr size_t WS_KEY  = WS_LIST + (size_t)NROWS * 4;  // u64[N]
constexpr size_t WS_MV   = WS_KEY + (size_t)NROWS * 8;   // float2[2][N]
constexpr size_t WS_KV   = WS_MV + (size_t)2 * NROWS * 8; // u64[2][N]
}

__device__ inline short f2bf(float v) {
  __hip_bfloat16 h = __float2bfloat16(v);
  return *reinterpret_cast<short*>(&h);
}
__device__ inline float bf2f(short s) {
  __hip_bfloat16 h;
  *reinterpret_cast<short*>(&h) = s;
  return __bfloat162float(h);
}
__device__ inline f32x4 mfma16(bf16x8 a, bf16x8 b, f32x4 c) {
  return __builtin_amdgcn_mfma_f32_16x16x32_bf16(a, b, c, 0, 0, 0);
}
__device__ inline unsigned int fflip(unsigned int b) {
  return b ^ ((unsigned int)((int)b >> 31) | 0x80000000u);
}

// ---------------- prep: init keyBest/loss/cnt, se (numpy pairwise), frag pack
__global__ __launch_bounds__(256) void vq_prep(const float* __restrict__ emb,
                                               float* __restrict__ se,
                                               short* __restrict__ ehB,
                                               short* __restrict__ elB,
                                               unsigned long long* __restrict__ keyBest,
                                               double* __restrict__ loss_accum,
                                               int* __restrict__ cnt) {
  #pragma clang fp contract(off)
  const int gid = blockIdx.x * 256 + (int)threadIdx.x;   // grid = 65536
  if (gid == 0) { *loss_accum = 0.0; *cnt = 0; }
  keyBest[gid] = ~0ull;

  if (gid < KCODES) {   // se[j]: proven pairwise pattern
    const float* e = emb + (size_t)gid * DDIM;
    float r[8];
    #pragma unroll
    for (int j = 0; j < 8; ++j) r[j] = e[j] * e[j];
    #pragma unroll
    for (int i = 8; i < DDIM; i += 8) {
      #pragma unroll
      for (int j = 0; j < 8; ++j) r[j] += e[i + j] * e[i + j];
    }
    se[gid] = ((r[0] + r[1]) + (r[2] + r[3])) + ((r[4] + r[5]) + (r[6] + r[7]));
  }

  // pack frag (t,dc): lane l holds e[t*16+(l&15)][dc*32+(l>>4)*8 + i]  (R5-R11)
  if (gid < 8192) {
    const int t  = gid >> 7;
    const int dc = (gid >> 6) & 1;
    const int l  = gid & 63;
    const int code = t * 16 + (l & 15);
    const int d0   = dc * 32 + (l >> 4) * 8;
    const float* ep = emb + (size_t)code * DDIM + d0;
    const size_t ob = ((size_t)(t * 2 + dc) * 64 + l) * 8;
    #pragma unroll
    for (int i = 0; i < 8; ++i) {
      const float v = ep[i];
      const short h = f2bf(v);
      ehB[ob + i] = h;
      elB[ob + i] = f2bf(v - bf2f(h));
    }
  }
}

// ---------------- fused sweep: block = 128 rows x 512 codes (K-split x2)
__global__ __launch_bounds__(256, 2) void vq_fused(const float* __restrict__ x,
                                                   const short* __restrict__ ehB,
                                                   const short* __restrict__ elB,
                                                   const float* __restrict__ se,
                                                   float2* __restrict__ mv,
                                                   unsigned long long* __restrict__ kv) {
  #pragma clang fp contract(off)
  __shared__ float sel[KCODES];
  const int tid  = (int)threadIdx.x;
  const int l    = tid & 63;
  const int wid  = tid >> 6;
  const int half = (int)blockIdx.x & 1;          // K-half: tiles [h*32, h*32+32)
  const int rblk = (int)blockIdx.x >> 1;
  #pragma unroll
  for (int i = 0; i < 4; ++i) sel[i * 256 + tid] = se[i * 256 + tid];
  __syncthreads();

  // A-fragments for 2 row-tiles (32 rows/wave)
  const int wrb = rblk * 128 + wid * 32;
  bf16x8 xh[2][2], xl[2][2];
  #pragma unroll
  for (int rt = 0; rt < 2; ++rt) {
    const float* xp = x + (size_t)(wrb + rt * 16 + (l & 15)) * DDIM + (l >> 4) * 8;
    #pragma unroll
    for (int dc = 0; dc < 2; ++dc) {
      const float4 v0 = *reinterpret_cast<const float4*>(xp + dc * 32);
      const float4 v1 = *reinterpret_cast<const float4*>(xp + dc * 32 + 4);
      const float vv[8] = {v0.x, v0.y, v0.z, v0.w, v1.x, v1.y, v1.z, v1.w};
      #pragma unroll
      for (int i = 0; i < 8; ++i) {
        const short h = f2bf(vv[i]);
        xh[rt][dc][i] = h;
        xl[rt][dc][i] = f2bf(vv[i] - bf2f(h));
      }
    }
  }

  float m1v[2][4], m2v[2][4];
  int   m1t[2][4];
  #pragma unroll
  for (int rt = 0; rt < 2; ++rt)
    #pragma unroll
    for (int r = 0; r < 4; ++r) { m1v[rt][r] = INFINITY; m2v[rt][r] = INFINITY; m1t[rt][r] = 0; }

  const size_t lb = (size_t)l * 8;
  const int t0 = half * 32;
#define FRAGLD(buf, tt, half2) \
  (*reinterpret_cast<const bf16x8*>((buf) + (size_t)(tt) * 1024 + (half2) * 512 + lb))

  // 2-deep pipeline: tiles t (cur) / t+1 (nxt) in flight while computing.
  bf16x8 c0 = FRAGLD(ehB, t0, 0), c1 = FRAGLD(ehB, t0, 1),
         c2 = FRAGLD(elB, t0, 0), c3 = FRAGLD(elB, t0, 1);
  bf16x8 n0 = FRAGLD(ehB, t0 + 1, 0), n1 = FRAGLD(ehB, t0 + 1, 1),
         n2 = FRAGLD(elB, t0 + 1, 0), n3 = FRAGLD(elB, t0 + 1, 1);

  const f32x4 kz = {0.f, 0.f, 0.f, 0.f};
  #pragma unroll 4
  for (int tt = 0; tt < 32; ++tt) {
    const int t = t0 + tt;
    const int tf = (tt + 2 < 32) ? t + 2 : t0 + 31;   // clamp (dup loads harmless)
    bf16x8 f0 = FRAGLD(ehB, tf, 0), f1 = FRAGLD(ehB, tf, 1),
           f2 = FRAGLD(elB, tf, 0), f3 = FRAGLD(elB, tf, 1);

    f32x4 a0, a1;   // interleave the two row-tiles: dep distance 2 on MFMA pipe
    a0 = mfma16(xh[0][0], c0, kz);  a1 = mfma16(xh[1][0], c0, kz);
    a0 = mfma16(xh[0][1], c1, a0);  a1 = mfma16(xh[1][1], c1, a1);
    a0 = mfma16(xh[0][0], c2, a0);  a1 = mfma16(xh[1][0], c2, a1);
    a0 = mfma16(xh[0][1], c3, a0);  a1 = mfma16(xh[1][1], c3, a1);
    a0 = mfma16(xl[0][0], c0, a0);  a1 = mfma16(xl[1][0], c0, a1);
    a0 = mfma16(xl[0][1], c1, a0);  a1 = mfma16(xl[1][1], c1, a1);

    const float sev = sel[t * 16 + (l & 15)];
    #pragma unroll
    for (int r = 0; r < 4; ++r) {
      {
        const float d = __builtin_fmaf(-2.0f, a0[r], sev);  // d' = se - 2*dot
        const bool c = d < m1v[0][r];
        m2v[0][r] = fminf(m2v[0][r], fmaxf(m1v[0][r], d));
        m1t[0][r] = c ? t : m1t[0][r];
        m1v[0][r] = fminf(m1v[0][r], d);
      }
      {
        const float d = __builtin_fmaf(-2.0f, a1[r], sev);
        const bool c = d < m1v[1][r];
        m2v[1][r] = fminf(m2v[1][r], fmaxf(m1v[1][r], d));
        m1t[1][r] = c ? t : m1t[1][r];
        m1v[1][r] = fminf(m1v[1][r], d);
      }
    }
    c0 = n0; c1 = n1; c2 = n2; c3 = n3;
    n0 = f0; n1 = f1; n2 = f2; n3 = f3;
  }
#undef FRAGLD

  // 16-lane merge (R6-R11-proven); emit per-half partials
  const int colbase = l & 15;
  #pragma unroll
  for (int rt = 0; rt < 2; ++rt) {
    #pragma unroll
    for (int r = 0; r < 4; ++r) {
      float m1 = m1v[rt][r], m2 = m2v[rt][r];
      unsigned long long key =
          ((unsigned long long)fflip(__float_as_uint(m1)) << 32)
          | (unsigned)(m1t[rt][r] * 16 + colbase);
      #pragma unroll
      for (int off = 1; off < 16; off <<= 1) {
        const unsigned long long ok = __shfl_xor(key, off, 16);
        const float om1 = __shfl_xor(m1, off, 16);
        const float om2 = __shfl_xor(m2, off, 16);
        m2 = fminf(fminf(m2, om2), fmaxf(m1, om1));
        m1 = fminf(m1, om1);
        key = (ok < key) ? ok : key;
      }
      if (colbase == 0) {
        const int row = wrb + rt * 16 + (l >> 4) * 4 + r;
        mv[(size_t)half * NROWS + row] = make_float2(m1, m2);
        kv[(size_t)half * NROWS + row] = key;
      }
    }
  }
}

// ---------------- combine halves + certificate + ballot compaction
__global__ __launch_bounds__(256) void vq_combine(const float2* __restrict__ mv,
                                                  const unsigned long long* __restrict__ kv,
                                                  int* __restrict__ bidx,
                                                  int* __restrict__ list,
                                                  int* __restrict__ cnt) {
  const int gid = blockIdx.x * 256 + (int)threadIdx.x;
  const int l = (int)threadIdx.x & 63;
  const float2 a = mv[gid];
  const float2 b = mv[(size_t)NROWS + gid];
  const unsigned long long ka = kv[gid];
  const unsigned long long kb = kv[(size_t)NROWS + gid];
  // union's two smallest over disjoint halves (exact rule)
  const float m1g = fminf(a.x, b.x);
  const float m2g = fminf(fminf(a.y, b.y), fmaxf(a.x, b.x));
  const unsigned long long kg = (ka < kb) ? ka : kb;   // (m1 asc, j asc)
  const bool cert = m2g > m1g + EPSB;
  bidx[gid] = cert ? (int)(kg & 0xffffffffull) : -1;

  const unsigned long long mask = __ballot(!cert);
  int base = 0;
  if (l == 0 && mask) base = atomicAdd(cnt, (int)__popcll(mask));
  base = __shfl(base, 0, 64);
  if (!cert) {
    const int off = (int)__popcll(mask & ((1ull << l) - 1ull));
    list[base + off] = gid;
  }
}

// ---------------- exact scan: lanes = rows, e staged in LDS (R11-frozen)
__global__ __launch_bounds__(256) void vq_exact(const float* __restrict__ x,
                                                const float* __restrict__ emb,
                                                const float* __restrict__ se,
                                                const int* __restrict__ list,
                                                const int* __restrict__ cnt,
                                                unsigned long long* __restrict__ keyBest) {
  #pragma clang fp contract(off)
  __shared__ __align__(16) float eL[64 * DDIM];   // 16 KB: this part's 64 codes
  const int part = (int)blockIdx.x & 15;
  const int j0 = part * 64;

  {  // stage: 64 contiguous e-rows, coalesced float4 copy
    const float4* src = reinterpret_cast<const float4*>(emb + (size_t)j0 * DDIM);
    float4* dst = reinterpret_cast<float4*>(eL);
    #pragma unroll
    for (int i = 0; i < 4; ++i)
      dst[i * 256 + (int)threadIdx.x] = src[i * 256 + (int)threadIdx.x];
  }
  __syncthreads();

  const int n = *cnt;
  const int l  = (int)threadIdx.x & 63;
  const int wv = (int)threadIdx.x >> 6;

  for (int rb = (int)blockIdx.x >> 4; rb * 256 < n; rb += 32) {
    const int idx = rb * 256 + wv * 64 + l;
    const bool act = idx < n;
    const int row = act ? list[idx] : 0;
    const float4* xr4 = reinterpret_cast<const float4*>(x + (size_t)row * DDIM);

    float xv[DDIM];   // x row -> regs once
    #pragma unroll
    for (int q = 0; q < 16; ++q) {
      const float4 v = xr4[q];
      xv[q * 4 + 0] = v.x; xv[q * 4 + 1] = v.y;
      xv[q * 4 + 2] = v.z; xv[q * 4 + 3] = v.w;
    }

    // sx: numpy pairwise 8-accumulator (R1-proven order)
    float rr[8];
    #pragma unroll
    for (int j = 0; j < 8; ++j) rr[j] = xv[j] * xv[j];
    #pragma unroll
    for (int i = 8; i < DDIM; i += 8) {
      #pragma unroll
      for (int j = 0; j < 8; ++j) rr[j] += xv[i + j] * xv[i + j];
    }
    const float sx = ((rr[0] + rr[1]) + (rr[2] + rr[3])) + ((rr[4] + rr[5]) + (rr[6] + rr[7]));

    unsigned long long best = ~0ull;
    #pragma unroll 1
    for (int g = 0; g < 16; ++g) {   // 16 groups of 4 codes; 4 chains
      const int jb = g * 4;
      const float4* e0 = reinterpret_cast<const float4*>(eL + (jb + 0) * DDIM);
      const float4* e1 = reinterpret_cast<const float4*>(eL + (jb + 1) * DDIM);
      const float4* e2 = reinterpret_cast<const float4*>(eL + (jb + 2) * DDIM);
      const float4* e3 = reinterpret_cast<const float4*>(eL + (jb + 3) * DDIM);
      float a0 = 0.f, a1 = 0.f, a2 = 0.f, a3 = 0.f;
      #pragma unroll
      for (int q = 0; q < 16; ++q) {   // per code: sequential d=0..63 (R1 chain)
        const float4 v0 = e0[q], v1 = e1[q], v2 = e2[q], v3 = e3[q];
        const float xa = xv[q * 4 + 0], xb = xv[q * 4 + 1];
        const float xc = xv[q * 4 + 2], xd = xv[q * 4 + 3];
        a0 = __builtin_fmaf(xa, v0.x, a0); a0 = __builtin_fmaf(xb, v0.y, a0);
        a0 = __builtin_fmaf(xc, v0.z, a0); a0 = __builtin_fmaf(xd, v0.w, a0);
        a1 = __builtin_fmaf(xa, v1.x, a1); a1 = __builtin_fmaf(xb, v1.y, a1);
        a1 = __builtin_fmaf(xc, v1.z, a1); a1 = __builtin_fmaf(xd, v1.w, a1);
        a2 = __builtin_fmaf(xa, v2.x, a2); a2 = __builtin_fmaf(xb, v2.y, a2);
        a2 = __builtin_fmaf(xc, v2.z, a2); a2 = __builtin_fmaf(xd, v2.w, a2);
        a3 = __builtin_fmaf(xa, v3.x, a3); a3 = __builtin_fmaf(xb, v3.y, a3);
        a3 = __builtin_fmaf(xc, v3.z, a3); a3 = __builtin_fmaf(xd, v3.w, a3);
      }
      const int j = j0 + jb;
      const float T0 = sx + se[j + 0];                    // fl(sx + se_j)
      const float T1 = sx + se[j + 1];
      const float T2 = sx + se[j + 2];
      const float T3 = sx + se[j + 3];
      const float di0 = __builtin_fmaf(-2.0f, a0, T0);    // fl(T - 2*acc)
      const float di1 = __builtin_fmaf(-2.0f, a1, T1);
      const float di2 = __builtin_fmaf(-2.0f, a2, T2);
      const float di3 = __builtin_fmaf(-2.0f, a3, T3);
      unsigned long long k;
      k = ((unsigned long long)fflip(__float_as_uint(di0)) << 32) | (unsigned)(j + 0);
      best = (k < best) ? k : best;
      k = ((unsigned long long)fflip(__float_as_uint(di1)) << 32) | (unsigned)(j + 1);
      best = (k < best) ? k : best;
      k = ((unsigned long long)fflip(__float_as_uint(di2)) << 32) | (unsigned)(j + 2);
      best = (k < best) ? k : best;
      k = ((unsigned long long)fflip(__float_as_uint(di3)) << 32) | (unsigned)(j + 3);
      best = (k < best) ? k : best;
    }
    if (act) atomicMin(&keyBest[row], best);   // (dist asc, j asc) == first-min
  }
}

// ---------------- finalize: 16 lanes x float4 per row (coalesced e-gather)
__global__ __launch_bounds__(256) void vq_finalize(const float* __restrict__ x,
                                                   const float* __restrict__ emb,
                                                   const int* __restrict__ bidx,
                                                   const unsigned long long* __restrict__ keyBest,
                                                   float* __restrict__ out,
                                                   double* __restrict__ loss_accum) {
  #pragma clang fp contract(off)
  __shared__ float wsum[4];
  const int tid = (int)threadIdx.x;
  const int l   = tid & 63;
  const int wid = tid >> 6;
  const int sub = l >> 4;    // row within the wave's quad
  const int q16 = l & 15;    // float4 slot within the row
  float lacc = 0.f;

  #pragma unroll
  for (int it = 0; it < 4; ++it) {   // block covers 64 rows
    const int row = blockIdx.x * 64 + it * 16 + wid * 4 + sub;
    int bi = bidx[row];
    if (bi < 0) bi = (int)(keyBest[row] & 0xffffffffull);
    const float4 xv = reinterpret_cast<const float4*>(x)[(size_t)row * 16 + q16];
    const float4 ev = reinterpret_cast<const float4*>(emb)[(size_t)bi * 16 + q16];
    const float da = ev.x - xv.x;
    const float db = ev.y - xv.y;
    const float dc = ev.z - xv.z;
    const float dd = ev.w - xv.w;
    float4 o;
    o.x = xv.x + da; o.y = xv.y + db; o.z = xv.z + dc; o.w = xv.w + dd;
    reinterpret_cast<float4*>(out)[(size_t)row * 16 + q16] = o;
    lacc += da * da + db * db + dc * dc + dd * dd;   // order-insensitive
    if (q16 == 0) out[(size_t)NROWS * DDIM + row] = (float)bi;
  }
  #pragma unroll
  for (int off = 32; off > 0; off >>= 1) lacc += __shfl_down(lacc, off, 64);
  if (l == 0) wsum[wid] = lacc;
  __syncthreads();
  if (tid == 0)
    atomicAdd(loss_accum, (double)(wsum[0] + wsum[1] + wsum[2] + wsum[3]));
}

// ---------------- scalars
__global__ void vq_scalars(const double* __restrict__ loss_accum,
                           float* __restrict__ out) {
  if (threadIdx.x == 0 && blockIdx.x == 0) {
    const double mm = *loss_accum / (double)((size_t)NROWS * DDIM);
    const float el = (float)mm;
    float* tail = out + (size_t)NROWS * DDIM + NROWS;
    tail[0] = 0.25f * el;
    tail[1] = el;
    tail[2] = 0.0f;
  }
}

// ============================================================================
extern "C" void kernel_launch(void* const* d_in, const int* in_sizes, int n_in,
                              void* d_out, int out_size, void* d_ws, size_t ws_size,
                              hipStream_t stream) {
  const float* x   = (const float*)d_in[0];  // [N, 64]
  const float* emb = (const float*)d_in[1];  // [K, 64]
  float* out = (float*)d_out;
  char* ws = (char*)d_ws;

  double* loss_accum = (double*)(ws + WS_LOSS);
  int*    cnt        = (int*)(ws + WS_CNT);
  float*  se         = (float*)(ws + WS_SE);
  short*  ehB        = (short*)(ws + WS_EHB);
  short*  elB        = (short*)(ws + WS_ELB);
  int*    bidx       = (int*)(ws + WS_BIDX);
  int*    list       = (int*)(ws + WS_LIST);
  unsigned long long* keyBest = (unsigned long long*)(ws + WS_KEY);
  float2* mv         = (float2*)(ws + WS_MV);
  unsigned long long* kv = (unsigned long long*)(ws + WS_KV);

  vq_prep<<<NROWS / 256, 256, 0, stream>>>(emb, se, ehB, elB, keyBest,
                                           loss_accum, cnt);
  vq_fused<<<(NROWS / 128) * 2, 256, 0, stream>>>(x, ehB, elB, se, mv, kv);
  vq_combine<<<NROWS / 256, 256, 0, stream>>>(mv, kv, bidx, list, cnt);
  vq_exact<<<512, 256, 0, stream>>>(x, emb, se, list, cnt, keyBest);
  vq_finalize<<<NROWS / 64, 256, 0, stream>>>(x, emb, bidx, keyBest, out,
                                              loss_accum);
  vq_scalars<<<1, 64, 0, stream>>>(loss_accum, out);
}

// Round 13
// 98.737 us; speedup vs baseline: 3.2370x; 1.1352x over previous
//
#include <hip/hip_runtime.h>
#include <hip/hip_bf16.h>
#include <math.h>

// VQ-VAE VectorQuantizer: B=32,T=2048,D=64,K=1024 -> N=65536 rows.
// Round 13: re-granularize the two remaining kernels (R12 = 112us, absmax 0.0):
//  1) vq_exact: 1-wave blocks, 32-code parts (8KB LDS), grid-strided tasks.
//     R12's exact was task-starved: 256 coarse tasks -> 1 wave/SIMD, occ 3.3%.
//     Now ~2048 tasks (64-row x 32-code) over 2048 one-wave blocks. Per-code
//     arithmetic verbatim from R11/R12 (4-chain groups, sequential d=0..63).
//  2) vq_fused: K-split x4 (16 tiles/block, grid 2048) -> occupancy cap 100%
//     (VGPR 56 allows 8 waves/SIMD; fused proved latency-bound R11->R12).
//     Combine: exact 4-way union rule m2g=min(secondmin{m1},min{m2}).
// EPSB=4e-5, prep/finalize/scalars byte-frozen (absmax 0.0 through R12).

typedef __attribute__((ext_vector_type(8))) short bf16x8;
typedef __attribute__((ext_vector_type(4))) float f32x4;

namespace {
constexpr int NROWS  = 65536;
constexpr int DDIM   = 64;
constexpr int KCODES = 1024;
constexpr float EPSB = 4e-5f;   // certificate band; bound ~1.05e-5

// ws layout (bytes) — ~7.6 MB
constexpr size_t WS_LOSS = 0;                            // double
constexpr size_t WS_CNT  = 64;                           // int
constexpr size_t WS_SE   = 256;                          // float[1024]
constexpr size_t WS_EHB  = 8192;                         // bf16 frags 128 KB
constexpr size_t WS_ELB  = WS_EHB + (size_t)65536 * 2;   // 128 KB
constexpr size_t WS_BIDX = WS_ELB + (size_t)65536 * 2;   // int[N]
constexpr size_t WS_LIST = WS_BIDX + (size_t)NROWS * 4;  // int[N]
constexpr size_t WS_KEY  = WS_LIST + (size_t)NROWS * 4;  // u64[N]
constexpr size_t WS_MV   = WS_KEY + (size_t)NROWS * 8;   // float2[4][N]
constexpr size_t WS_KV   = WS_MV + (size_t)4 * NROWS * 8; // u64[4][N]
}

__device__ inline short f2bf(float v) {
  __hip_bfloat16 h = __float2bfloat16(v);
  return *reinterpret_cast<short*>(&h);
}
__device__ inline float bf2f(short s) {
  __hip_bfloat16 h;
  *reinterpret_cast<short*>(&h) = s;
  return __bfloat162float(h);
}
__device__ inline f32x4 mfma16(bf16x8 a, bf16x8 b, f32x4 c) {
  return __builtin_amdgcn_mfma_f32_16x16x32_bf16(a, b, c, 0, 0, 0);
}
__device__ inline unsigned int fflip(unsigned int b) {
  return b ^ ((unsigned int)((int)b >> 31) | 0x80000000u);
}

// ---------------- prep: init keyBest/loss/cnt, se (numpy pairwise), frag pack
__global__ __launch_bounds__(256) void vq_prep(const float* __restrict__ emb,
                                               float* __restrict__ se,
                                               short* __restrict__ ehB,
                                               short* __restrict__ elB,
                                               unsigned long long* __restrict__ keyBest,
                                               double* __restrict__ loss_accum,
                                               int* __restrict__ cnt) {
  #pragma clang fp contract(off)
  const int gid = blockIdx.x * 256 + (int)threadIdx.x;   // grid = 65536
  if (gid == 0) { *loss_accum = 0.0; *cnt = 0; }
  keyBest[gid] = ~0ull;

  if (gid < KCODES) {   // se[j]: proven pairwise pattern
    const float* e = emb + (size_t)gid * DDIM;
    float r[8];
    #pragma unroll
    for (int j = 0; j < 8; ++j) r[j] = e[j] * e[j];
    #pragma unroll
    for (int i = 8; i < DDIM; i += 8) {
      #pragma unroll
      for (int j = 0; j < 8; ++j) r[j] += e[i + j] * e[i + j];
    }
    se[gid] = ((r[0] + r[1]) + (r[2] + r[3])) + ((r[4] + r[5]) + (r[6] + r[7]));
  }

  // pack frag (t,dc): lane l holds e[t*16+(l&15)][dc*32+(l>>4)*8 + i]  (R5-R12)
  if (gid < 8192) {
    const int t  = gid >> 7;
    const int dc = (gid >> 6) & 1;
    const int l  = gid & 63;
    const int code = t * 16 + (l & 15);
    const int d0   = dc * 32 + (l >> 4) * 8;
    const float* ep = emb + (size_t)code * DDIM + d0;
    const size_t ob = ((size_t)(t * 2 + dc) * 64 + l) * 8;
    #pragma unroll
    for (int i = 0; i < 8; ++i) {
      const float v = ep[i];
      const short h = f2bf(v);
      ehB[ob + i] = h;
      elB[ob + i] = f2bf(v - bf2f(h));
    }
  }
}

// ---------------- fused sweep: block = 128 rows x 256 codes (K-split x4)
__global__ __launch_bounds__(256, 2) void vq_fused(const float* __restrict__ x,
                                                   const short* __restrict__ ehB,
                                                   const short* __restrict__ elB,
                                                   const float* __restrict__ se,
                                                   float2* __restrict__ mv,
                                                   unsigned long long* __restrict__ kv) {
  #pragma clang fp contract(off)
  __shared__ float sel[256];                     // this quarter's se values
  const int tid  = (int)threadIdx.x;
  const int l    = tid & 63;
  const int wid  = tid >> 6;
  const int quar = (int)blockIdx.x & 3;          // K-quarter: tiles [q*16, q*16+16)
  const int rblk = (int)blockIdx.x >> 2;
  const int t0   = quar * 16;
  sel[tid] = se[t0 * 16 + tid];
  __syncthreads();

  // A-fragments for 2 row-tiles (32 rows/wave)
  const int wrb = rblk * 128 + wid * 32;
  bf16x8 xh[2][2], xl[2][2];
  #pragma unroll
  for (int rt = 0; rt < 2; ++rt) {
    const float* xp = x + (size_t)(wrb + rt * 16 + (l & 15)) * DDIM + (l >> 4) * 8;
    #pragma unroll
    for (int dc = 0; dc < 2; ++dc) {
      const float4 v0 = *reinterpret_cast<const float4*>(xp + dc * 32);
      const float4 v1 = *reinterpret_cast<const float4*>(xp + dc * 32 + 4);
      const float vv[8] = {v0.x, v0.y, v0.z, v0.w, v1.x, v1.y, v1.z, v1.w};
      #pragma unroll
      for (int i = 0; i < 8; ++i) {
        const short h = f2bf(vv[i]);
        xh[rt][dc][i] = h;
        xl[rt][dc][i] = f2bf(vv[i] - bf2f(h));
      }
    }
  }

  float m1v[2][4], m2v[2][4];
  int   m1t[2][4];
  #pragma unroll
  for (int rt = 0; rt < 2; ++rt)
    #pragma unroll
    for (int r = 0; r < 4; ++r) { m1v[rt][r] = INFINITY; m2v[rt][r] = INFINITY; m1t[rt][r] = 0; }

  const size_t lb = (size_t)l * 8;
#define FRAGLD(buf, tt, half2) \
  (*reinterpret_cast<const bf16x8*>((buf) + (size_t)(tt) * 1024 + (half2) * 512 + lb))

  // 2-deep pipeline: tiles t (cur) / t+1 (nxt) in flight while computing.
  bf16x8 c0 = FRAGLD(ehB, t0, 0), c1 = FRAGLD(ehB, t0, 1),
         c2 = FRAGLD(elB, t0, 0), c3 = FRAGLD(elB, t0, 1);
  bf16x8 n0 = FRAGLD(ehB, t0 + 1, 0), n1 = FRAGLD(ehB, t0 + 1, 1),
         n2 = FRAGLD(elB, t0 + 1, 0), n3 = FRAGLD(elB, t0 + 1, 1);

  const f32x4 kz = {0.f, 0.f, 0.f, 0.f};
  #pragma unroll 4
  for (int tt = 0; tt < 16; ++tt) {
    const int t = t0 + tt;
    const int tf = (tt + 2 < 16) ? t + 2 : t0 + 15;   // clamp (dup loads harmless)
    bf16x8 f0 = FRAGLD(ehB, tf, 0), f1 = FRAGLD(ehB, tf, 1),
           f2 = FRAGLD(elB, tf, 0), f3 = FRAGLD(elB, tf, 1);

    f32x4 a0, a1;   // interleave the two row-tiles: dep distance 2 on MFMA pipe
    a0 = mfma16(xh[0][0], c0, kz);  a1 = mfma16(xh[1][0], c0, kz);
    a0 = mfma16(xh[0][1], c1, a0);  a1 = mfma16(xh[1][1], c1, a1);
    a0 = mfma16(xh[0][0], c2, a0);  a1 = mfma16(xh[1][0], c2, a1);
    a0 = mfma16(xh[0][1], c3, a0);  a1 = mfma16(xh[1][1], c3, a1);
    a0 = mfma16(xl[0][0], c0, a0);  a1 = mfma16(xl[1][0], c0, a1);
    a0 = mfma16(xl[0][1], c1, a0);  a1 = mfma16(xl[1][1], c1, a1);

    const float sev = sel[tt * 16 + (l & 15)];
    #pragma unroll
    for (int r = 0; r < 4; ++r) {
      {
        const float d = __builtin_fmaf(-2.0f, a0[r], sev);  // d' = se - 2*dot
        const bool c = d < m1v[0][r];
        m2v[0][r] = fminf(m2v[0][r], fmaxf(m1v[0][r], d));
        m1t[0][r] = c ? t : m1t[0][r];
        m1v[0][r] = fminf(m1v[0][r], d);
      }
      {
        const float d = __builtin_fmaf(-2.0f, a1[r], sev);
        const bool c = d < m1v[1][r];
        m2v[1][r] = fminf(m2v[1][r], fmaxf(m1v[1][r], d));
        m1t[1][r] = c ? t : m1t[1][r];
        m1v[1][r] = fminf(m1v[1][r], d);
      }
    }
    c0 = n0; c1 = n1; c2 = n2; c3 = n3;
    n0 = f0; n1 = f1; n2 = f2; n3 = f3;
  }
#undef FRAGLD

  // 16-lane merge (R6-R12-proven); emit per-quarter partials
  const int colbase = l & 15;
  #pragma unroll
  for (int rt = 0; rt < 2; ++rt) {
    #pragma unroll
    for (int r = 0; r < 4; ++r) {
      float m1 = m1v[rt][r], m2 = m2v[rt][r];
      unsigned long long key =
          ((unsigned long long)fflip(__float_as_uint(m1)) << 32)
          | (unsigned)(m1t[rt][r] * 16 + colbase);
      #pragma unroll
      for (int off = 1; off < 16; off <<= 1) {
        const unsigned long long ok = __shfl_xor(key, off, 16);
        const float om1 = __shfl_xor(m1, off, 16);
        const float om2 = __shfl_xor(m2, off, 16);
        m2 = fminf(fminf(m2, om2), fmaxf(m1, om1));
        m1 = fminf(m1, om1);
        key = (ok < key) ? ok : key;
      }
      if (colbase == 0) {
        const int row = wrb + rt * 16 + (l >> 4) * 4 + r;
        mv[(size_t)quar * NROWS + row] = make_float2(m1, m2);
        kv[(size_t)quar * NROWS + row] = key;
      }
    }
  }
}

// ---------------- combine 4 quarters + certificate + ballot compaction
__global__ __launch_bounds__(256) void vq_combine(const float2* __restrict__ mv,
                                                  const unsigned long long* __restrict__ kv,
                                                  int* __restrict__ bidx,
                                                  int* __restrict__ list,
                                                  int* __restrict__ cnt) {
  const int gid = blockIdx.x * 256 + (int)threadIdx.x;
  const int l = (int)threadIdx.x & 63;
  const float2 A = mv[gid];
  const float2 B = mv[(size_t)NROWS + gid];
  const float2 C = mv[(size_t)2 * NROWS + gid];
  const float2 D = mv[(size_t)3 * NROWS + gid];
  unsigned long long kg = kv[gid];
  {
    unsigned long long k2 = kv[(size_t)NROWS + gid];     kg = (k2 < kg) ? k2 : kg;
    k2 = kv[(size_t)2 * NROWS + gid];                    kg = (k2 < kg) ? k2 : kg;
    k2 = kv[(size_t)3 * NROWS + gid];                    kg = (k2 < kg) ? k2 : kg;
  }
  // union's two smallest over 4 disjoint quarters (exact tournament rule)
  const float lo1 = fminf(A.x, B.x), hi1 = fmaxf(A.x, B.x);
  const float lo2 = fminf(C.x, D.x), hi2 = fmaxf(C.x, D.x);
  const float m1g = fminf(lo1, lo2);
  const float sec = fminf(fmaxf(lo1, lo2), fminf(hi1, hi2));  // secondmin{m1}
  const float m2g = fminf(sec, fminf(fminf(A.y, B.y), fminf(C.y, D.y)));
  const bool cert = m2g > m1g + EPSB;
  bidx[gid] = cert ? (int)(kg & 0xffffffffull) : -1;

  const unsigned long long mask = __ballot(!cert);
  int base = 0;
  if (l == 0 && mask) base = atomicAdd(cnt, (int)__popcll(mask));
  base = __shfl(base, 0, 64);
  if (!cert) {
    const int off = (int)__popcll(mask & ((1ull << l) - 1ull));
    list[base + off] = gid;
  }
}

// ---------------- exact scan: 1-wave blocks, lanes = rows, 32-code LDS parts,
// grid-strided tasks. Per-(row,code) arithmetic verbatim from R11/R12.
__global__ __launch_bounds__(64) void vq_exact(const float* __restrict__ x,
                                               const float* __restrict__ emb,
                                               const float* __restrict__ se,
                                               const int* __restrict__ list,
                                               const int* __restrict__ cnt,
                                               unsigned long long* __restrict__ keyBest) {
  #pragma clang fp contract(off)
  __shared__ __align__(16) float eL[32 * DDIM];   // 8 KB: one part's 32 codes
  const int n = *cnt;
  if (n == 0) return;
  const int nrb = (n + 63) >> 6;
  const int ntasks = nrb * 32;
  const int l = (int)threadIdx.x;                 // 0..63

  for (int t = (int)blockIdx.x; t < ntasks; t += (int)gridDim.x) {
    const int part = t & 31;
    const int rb   = t >> 5;
    const int j0   = part * 32;

    {  // stage this part's 32 e-rows (coalesced float4)
      const float4* src = reinterpret_cast<const float4*>(emb + (size_t)j0 * DDIM);
      float4* dst = reinterpret_cast<float4*>(eL);
      #pragma unroll
      for (int i = 0; i < 8; ++i) dst[i * 64 + l] = src[i * 64 + l];
    }
    __syncthreads();

    const int idx = rb * 64 + l;
    const bool act = idx < n;
    const int row = act ? list[idx] : 0;
    const float4* xr4 = reinterpret_cast<const float4*>(x + (size_t)row * DDIM);

    float xv[DDIM];   // x row -> regs once
    #pragma unroll
    for (int q = 0; q < 16; ++q) {
      const float4 v = xr4[q];
      xv[q * 4 + 0] = v.x; xv[q * 4 + 1] = v.y;
      xv[q * 4 + 2] = v.z; xv[q * 4 + 3] = v.w;
    }

    // sx: numpy pairwise 8-accumulator (R1-proven order)
    float rr[8];
    #pragma unroll
    for (int j = 0; j < 8; ++j) rr[j] = xv[j] * xv[j];
    #pragma unroll
    for (int i = 8; i < DDIM; i += 8) {
      #pragma unroll
      for (int j = 0; j < 8; ++j) rr[j] += xv[i + j] * xv[i + j];
    }
    const float sx = ((rr[0] + rr[1]) + (rr[2] + rr[3])) + ((rr[4] + rr[5]) + (rr[6] + rr[7]));

    unsigned long long best = ~0ull;
    #pragma unroll 1
    for (int g = 0; g < 8; ++g) {   // 8 groups of 4 codes; 4 chains
      const int jb = g * 4;
      const float4* e0 = reinterpret_cast<const float4*>(eL + (jb + 0) * DDIM);
      const float4* e1 = reinterpret_cast<const float4*>(eL + (jb + 1) * DDIM);
      const float4* e2 = reinterpret_cast<const float4*>(eL + (jb + 2) * DDIM);
      const float4* e3 = reinterpret_cast<const float4*>(eL + (jb + 3) * DDIM);
      float a0 = 0.f, a1 = 0.f, a2 = 0.f, a3 = 0.f;
      #pragma unroll
      for (int q = 0; q < 16; ++q) {   // per code: sequential d=0..63 (R1 chain)
        const float4 v0 = e0[q], v1 = e1[q], v2 = e2[q], v3 = e3[q];
        const float xa = xv[q * 4 + 0], xb = xv[q * 4 + 1];
        const float xc = xv[q * 4 + 2], xd = xv[q * 4 + 3];
        a0 = __builtin_fmaf(xa, v0.x, a0); a0 = __builtin_fmaf(xb, v0.y, a0);
        a0 = __builtin_fmaf(xc, v0.z, a0); a0 = __builtin_fmaf(xd, v0.w, a0);
        a1 = __builtin_fmaf(xa, v1.x, a1); a1 = __builtin_fmaf(xb, v1.y, a1);
        a1 = __builtin_fmaf(xc, v1.z, a1); a1 = __builtin_fmaf(xd, v1.w, a1);
        a2 = __builtin_fmaf(xa, v2.x, a2); a2 = __builtin_fmaf(xb, v2.y, a2);
        a2 = __builtin_fmaf(xc, v2.z, a2); a2 = __builtin_fmaf(xd, v2.w, a2);
        a3 = __builtin_fmaf(xa, v3.x, a3); a3 = __builtin_fmaf(xb, v3.y, a3);
        a3 = __builtin_fmaf(xc, v3.z, a3); a3 = __builtin_fmaf(xd, v3.w, a3);
      }
      const int j = j0 + jb;
      const float T0 = sx + se[j + 0];                    // fl(sx + se_j)
      const float T1 = sx + se[j + 1];
      const float T2 = sx + se[j + 2];
      const float T3 = sx + se[j + 3];
      const float di0 = __builtin_fmaf(-2.0f, a0, T0);    // fl(T - 2*acc)
      const float di1 = __builtin_fmaf(-2.0f, a1, T1);
      const float di2 = __builtin_fmaf(-2.0f, a2, T2);
      const float di3 = __builtin_fmaf(-2.0f, a3, T3);
      unsigned long long k;
      k = ((unsigned long long)fflip(__float_as_uint(di0)) << 32) | (unsigned)(j + 0);
      best = (k < best) ? k : best;
      k = ((unsigned long long)fflip(__float_as_uint(di1)) << 32) | (unsigned)(j + 1);
      best = (k < best) ? k : best;
      k = ((unsigned long long)fflip(__float_as_uint(di2)) << 32) | (unsigned)(j + 2);
      best = (k < best) ? k : best;
      k = ((unsigned long long)fflip(__float_as_uint(di3)) << 32) | (unsigned)(j + 3);
      best = (k < best) ? k : best;
    }
    if (act) atomicMin(&keyBest[row], best);   // (dist asc, j asc) == first-min
    __syncthreads();                           // eL reuse barrier (1-wave: cheap)
  }
}

// ---------------- finalize: 16 lanes x float4 per row (coalesced e-gather)
__global__ __launch_bounds__(256) void vq_finalize(const float* __restrict__ x,
                                                   const float* __restrict__ emb,
                                                   const int* __restrict__ bidx,
                                                   const unsigned long long* __restrict__ keyBest,
                                                   float* __restrict__ out,
                                                   double* __restrict__ loss_accum) {
  #pragma clang fp contract(off)
  __shared__ float wsum[4];
  const int tid = (int)threadIdx.x;
  const int l   = tid & 63;
  const int wid = tid >> 6;
  const int sub = l >> 4;    // row within the wave's quad
  const int q16 = l & 15;    // float4 slot within the row
  float lacc = 0.f;

  #pragma unroll
  for (int it = 0; it < 4; ++it) {   // block covers 64 rows
    const int row = blockIdx.x * 64 + it * 16 + wid * 4 + sub;
    int bi = bidx[row];
    if (bi < 0) bi = (int)(keyBest[row] & 0xffffffffull);
    const float4 xv = reinterpret_cast<const float4*>(x)[(size_t)row * 16 + q16];
    const float4 ev = reinterpret_cast<const float4*>(emb)[(size_t)bi * 16 + q16];
    const float da = ev.x - xv.x;
    const float db = ev.y - xv.y;
    const float dc = ev.z - xv.z;
    const float dd = ev.w - xv.w;
    float4 o;
    o.x = xv.x + da; o.y = xv.y + db; o.z = xv.z + dc; o.w = xv.w + dd;
    reinterpret_cast<float4*>(out)[(size_t)row * 16 + q16] = o;
    lacc += da * da + db * db + dc * dc + dd * dd;   // order-insensitive
    if (q16 == 0) out[(size_t)NROWS * DDIM + row] = (float)bi;
  }
  #pragma unroll
  for (int off = 32; off > 0; off >>= 1) lacc += __shfl_down(lacc, off, 64);
  if (l == 0) wsum[wid] = lacc;
  __syncthreads();
  if (tid == 0)
    atomicAdd(loss_accum, (double)(wsum[0] + wsum[1] + wsum[2] + wsum[3]));
}

// ---------------- scalars
__global__ void vq_scalars(const double* __restrict__ loss_accum,
                           float* __restrict__ out) {
  if (threadIdx.x == 0 && blockIdx.x == 0) {
    const double mm = *loss_accum / (double)((size_t)NROWS * DDIM);
    const float el = (float)mm;
    float* tail = out + (size_t)NROWS * DDIM + NROWS;
    tail[0] = 0.25f * el;
    tail[1] = el;
    tail[2] = 0.0f;
  }
}

// ============================================================================
extern "C" void kernel_launch(void* const* d_in, const int* in_sizes, int n_in,
                              void* d_out, int out_size, void* d_ws, size_t ws_size,
                              hipStream_t stream) {
  const float* x   = (const float*)d_in[0];  // [N, 64]
  const float* emb = (const float*)d_in[1];  // [K, 64]
  float* out = (float*)d_out;
  char* ws = (char*)d_ws;

  double* loss_accum = (double*)(ws + WS_LOSS);
  int*    cnt        = (int*)(ws + WS_CNT);
  float*  se         = (float*)(ws + WS_SE);
  short*  ehB        = (short*)(ws + WS_EHB);
  short*  elB        = (short*)(ws + WS_ELB);
  int*    bidx       = (int*)(ws + WS_BIDX);
  int*    list       = (int*)(ws + WS_LIST);
  unsigned long long* keyBest = (unsigned long long*)(ws + WS_KEY);
  float2* mv         = (float2*)(ws + WS_MV);
  unsigned long long* kv = (unsigned long long*)(ws + WS_KV);

  vq_prep<<<NROWS / 256, 256, 0, stream>>>(emb, se, ehB, elB, keyBest,
                                           loss_accum, cnt);
  vq_fused<<<(NROWS / 128) * 4, 256, 0, stream>>>(x, ehB, elB, se, mv, kv);
  vq_combine<<<NROWS / 256, 256, 0, stream>>>(mv, kv, bidx, list, cnt);
  vq_exact<<<2048, 64, 0, stream>>>(x, emb, se, list, cnt, keyBest);
  vq_finalize<<<NROWS / 64, 256, 0, stream>>>(x, emb, bidx, keyBest, out,
                                              loss_accum);
  vq_scalars<<<1, 64, 0, stream>>>(loss_accum, out);
}